// Round 1
// baseline (2081.536 us; speedup 1.0000x reference)
//
#include <hip/hip_runtime.h>
#include <stdint.h>

namespace {
constexpr int B    = 16;
constexpr int N    = 25200;
constexpr int NC   = 80;
constexpr int ROW  = 85;
constexpr float CONF  = 0.25f;
constexpr float IOU_T = 0.45f;
constexpr float MAX_WH = 7680.0f;
constexpr int MAX_DET = 300;
constexpr int KSEL = 4096;
constexpr int CAP  = 6144;          // candidate capacity per image (>= KSEL + bin overshoot)
constexpr int NBINS = 4352;         // (bits - bits(0.25)) >> 12 ranges 0..4096
constexpr uint32_t BIN_BASE = 0x3E800000u;  // __float_as_uint(0.25f)

// ws layout (bytes)
constexpr size_t OBOX_OFF  = 0;
constexpr size_t OBOX_SZ   = (size_t)B * CAP * 16;          // float4
constexpr size_t OSC_OFF   = OBOX_OFF + OBOX_SZ;
constexpr size_t OSC_SZ    = (size_t)B * CAP * 4;
constexpr size_t OFI_OFF   = OSC_OFF + OSC_SZ;
constexpr size_t OFI_SZ    = (size_t)B * CAP * 4;
constexpr size_t HIST_OFF  = OFI_OFF + OFI_SZ;
constexpr size_t HIST_SZ   = (size_t)B * NBINS * 4;
constexpr size_t CNT_OFF   = HIST_OFF + HIST_SZ;
constexpr size_t CNT_SZ    = (size_t)B * 4;
constexpr size_t THR_OFF   = CNT_OFF + CNT_SZ;
}

// ---------------- Pass 1: per-image histogram of score fp32 bit-bins ----------------
__global__ __launch_bounds__(256) void k_hist(const float* __restrict__ pred,
                                              int* __restrict__ hist) {
#pragma clang fp contract(off)
  __shared__ int lh[NBINS];
  for (int i = threadIdx.x; i < NBINS; i += 256) lh[i] = 0;
  __syncthreads();
  const int img = blockIdx.y;
  const int a = blockIdx.x * 256 + threadIdx.x;
  if (a < N) {
    const float* p = pred + ((size_t)img * N + a) * ROW;
    const float obj = p[4];
    for (int c = 0; c < NC; ++c) {
      float s = obj * p[5 + c];
      if (s > CONF) {
        uint32_t b = (__float_as_uint(s) - BIN_BASE) >> 12;
        if (b > NBINS - 1) b = NBINS - 1;
        atomicAdd(&lh[b], 1);
      }
    }
  }
  __syncthreads();
  int* gh = hist + (size_t)img * NBINS;
  for (int i = threadIdx.x; i < NBINS; i += 256) {
    int v = lh[i];
    if (v) atomicAdd(&gh[i], v);
  }
}

// ---------------- Pass 2: select per-image pivot threshold (>= KSEL included) -------
__global__ __launch_bounds__(256) void k_pivot(const int* __restrict__ hist,
                                               float* __restrict__ thr) {
  __shared__ int psum[256];
  const int img = blockIdx.x;
  const int* gh = hist + (size_t)img * NBINS;
  const int t = threadIdx.x;
  constexpr int CH = NBINS / 256;  // 17
  int s = 0;
  for (int b = t * CH; b < t * CH + CH; ++b) s += gh[b];
  psum[t] = s;
  __syncthreads();
  if (t == 0) {
    int cum = 0, bstar = 0;
    bool found = false;
    for (int c = 255; c >= 0 && !found; --c) {
      if (cum + psum[c] >= KSEL) {
        for (int b = c * CH + CH - 1; b >= c * CH; --b) {
          cum += gh[b];
          if (cum >= KSEL) { bstar = b; found = true; break; }
        }
      } else {
        cum += psum[c];
      }
    }
    thr[img] = __uint_as_float(BIN_BASE + ((uint32_t)bstar << 12));
  }
}

// ---------------- Pass 3: compact candidates above pivot ----------------------------
__global__ __launch_bounds__(256) void k_compact(const float* __restrict__ pred,
                                                 const float* __restrict__ thr,
                                                 int* __restrict__ cnt,
                                                 float4* __restrict__ obox,
                                                 float* __restrict__ oscore,
                                                 int* __restrict__ ofidx) {
#pragma clang fp contract(off)
  const int img = blockIdx.y;
  const int a = blockIdx.x * 256 + threadIdx.x;
  if (a >= N) return;
  const float* p = pred + ((size_t)img * N + a) * ROW;
  const float cx = p[0], cy = p[1], w = p[2], h = p[3], obj = p[4];
  const float hw = w * 0.5f, hh = h * 0.5f;
  const float x1 = cx - hw, y1 = cy - hh, x2 = cx + hw, y2 = cy + hh;
  const float th = thr[img];
  for (int c = 0; c < NC; ++c) {
    float s = obj * p[5 + c];
    if (s > CONF && s >= th) {
      int pos = atomicAdd(&cnt[img], 1);
      if (pos < CAP) {
        float off = (float)c * MAX_WH;
        size_t o = (size_t)img * CAP + pos;
        obox[o] = make_float4(x1 + off, y1 + off, x2 + off, y2 + off);
        oscore[o] = s;
        ofidx[o] = a * NC + c;
      }
    }
  }
}

// ---------------- Pass 4: greedy NMS, one block per image ---------------------------
__global__ __launch_bounds__(1024) void k_nms(const int* __restrict__ cnt,
                                              const float4* __restrict__ obox,
                                              const float* __restrict__ oscore,
                                              const int* __restrict__ ofidx,
                                              float* __restrict__ out) {
#pragma clang fp contract(off)
  constexpr int PT = CAP / 1024;  // 6 candidates per thread
  __shared__ unsigned long long wmax[16];
  __shared__ unsigned long long sbest;
  __shared__ float4 recBox[MAX_DET];
  __shared__ float  recScore[MAX_DET];
  __shared__ int    recFidx[MAX_DET];

  const int img = blockIdx.x;
  const int tid = threadIdx.x;
  const int n = min(cnt[img], CAP);

  float4 box[PT];
  float  area[PT];
  unsigned long long key[PT];

  for (int j = 0; j < PT; ++j) {
    const int c = tid + j * 1024;
    if (c < n) {
      const size_t o = (size_t)img * CAP + c;
      const float4 b = obox[o];
      const float s = oscore[o];
      const int f = ofidx[o];
      box[j] = b;
      area[j] = (b.z - b.x) * (b.w - b.y);
      key[j] = ((unsigned long long)__float_as_uint(s) << 32) |
               (unsigned long long)(0xFFFFFFFFu - (uint32_t)f);
    } else {
      key[j] = 0ull;
      box[j] = make_float4(0.f, 0.f, 0.f, 0.f);
      area[j] = 0.f;
    }
  }

  const int lane = tid & 63;
  const int wid = tid >> 6;

  for (int it = 0; it < MAX_DET; ++it) {
    // local max key
    unsigned long long k = key[0];
    for (int j = 1; j < PT; ++j) k = (key[j] > k) ? key[j] : k;
    // wave butterfly max
    for (int d = 32; d > 0; d >>= 1) {
      unsigned long long o = __shfl_xor(k, d, 64);
      k = (o > k) ? o : k;
    }
    if (lane == 0) wmax[wid] = k;
    __syncthreads();
    if (tid == 0) {
      unsigned long long bk = wmax[0];
      for (int wv = 1; wv < 16; ++wv) bk = (wmax[wv] > bk) ? wmax[wv] : bk;
      sbest = bk;
      recScore[it] = (bk == 0ull) ? 0.0f : __uint_as_float((uint32_t)(bk >> 32));
      recFidx[it] = (bk == 0ull) ? 0 : (int)(0xFFFFFFFFu - (uint32_t)(bk & 0xFFFFFFFFu));
    }
    __syncthreads();
    const unsigned long long best = sbest;
    if (best != 0ull) {
      for (int j = 0; j < PT; ++j) {
        if (key[j] == best) {
          recBox[it] = box[j];
          key[j] = 0ull;  // chosen: always removed
        }
      }
    }
    __syncthreads();
    const float bs = recScore[it];
    if (best != 0ull && bs > CONF) {
      const float4 bb = recBox[it];
      const float area_b = (bb.z - bb.x) * (bb.w - bb.y);
      for (int j = 0; j < PT; ++j) {
        if (key[j] != 0ull) {
          float ltx = fmaxf(bb.x, box[j].x);
          float lty = fmaxf(bb.y, box[j].y);
          float rbx = fminf(bb.z, box[j].z);
          float rby = fminf(bb.w, box[j].w);
          float ww = fmaxf(rbx - ltx, 0.0f);
          float hh = fmaxf(rby - lty, 0.0f);
          float inter = ww * hh;
          float iou = inter / (area_b + area[j] - inter + 1e-7f);
          if (iou > IOU_T) key[j] = 0ull;
        }
      }
    }
    __syncthreads();  // wmax/rec stable before next iteration
  }

  // emit output rows (always write all rows — d_out is poisoned before timing)
  for (int i = tid; i < MAX_DET; i += 1024) {
    const float s = recScore[i];
    float* o = out + ((size_t)img * MAX_DET + i) * 6;
    if (s > CONF) {
      const int f = recFidx[i];
      const int cls = f % NC;
      const float clsf = (float)cls;
      const float off = clsf * MAX_WH;
      const float4 bb = recBox[i];
      o[0] = bb.x - off;
      o[1] = bb.y - off;
      o[2] = bb.z - off;
      o[3] = bb.w - off;
      o[4] = s;
      o[5] = clsf;
    } else {
      o[0] = 0.f; o[1] = 0.f; o[2] = 0.f; o[3] = 0.f; o[4] = 0.f; o[5] = 0.f;
    }
  }
}

extern "C" void kernel_launch(void* const* d_in, const int* in_sizes, int n_in,
                              void* d_out, int out_size, void* d_ws, size_t ws_size,
                              hipStream_t stream) {
  const float* pred = (const float*)d_in[0];
  float* out = (float*)d_out;
  char* ws = (char*)d_ws;

  float4* obox  = (float4*)(ws + OBOX_OFF);
  float* oscore = (float*)(ws + OSC_OFF);
  int*   ofidx  = (int*)(ws + OFI_OFF);
  int*   hist   = (int*)(ws + HIST_OFF);
  int*   cnt    = (int*)(ws + CNT_OFF);
  float* thr    = (float*)(ws + THR_OFF);

  // zero histogram + counters (d_ws is NOT re-poisoned/zeroed between replays)
  hipMemsetAsync(hist, 0, HIST_SZ + CNT_SZ, stream);

  dim3 gbulk((N + 255) / 256, B);
  k_hist<<<gbulk, 256, 0, stream>>>(pred, hist);
  k_pivot<<<B, 256, 0, stream>>>(hist, thr);
  k_compact<<<gbulk, 256, 0, stream>>>(pred, thr, cnt, obox, oscore, ofidx);
  k_nms<<<B, 1024, 0, stream>>>(cnt, obox, oscore, ofidx, out);
}

// Round 2
// 917.909 us; speedup vs baseline: 2.2677x; 2.2677x over previous
//
#include <hip/hip_runtime.h>
#include <stdint.h>

namespace {
typedef unsigned long long u64;
constexpr int B    = 16;
constexpr int N    = 25200;
constexpr int NC   = 80;
constexpr int ROW  = 85;
constexpr float CONF  = 0.25f;
constexpr float IOU_T = 0.45f;
constexpr float MAX_WH = 7680.0f;
constexpr int MAX_DET = 300;
constexpr int KSEL = 4096;
constexpr int CAP  = 6144;          // candidate capacity per image
constexpr int CAPM = 448;           // per-class member fast-path capacity
constexpr int NBINS = 4352;
constexpr uint32_t BIN_BASE = 0x3E800000u;  // bits(0.25f)

// ws layout (bytes), all 16B-aligned
constexpr size_t CREC_OFF   = 0;
constexpr size_t CREC_SZ    = (size_t)B * CAP * 8;      // u64 key records
constexpr size_t SKEY_OFF   = CREC_OFF + CREC_SZ;
constexpr size_t SKEY_SZ    = (size_t)B * 4096 * 8;     // sorted keys (top 4096)
constexpr size_t SOBOX_OFF  = SKEY_OFF + SKEY_SZ;
constexpr size_t SOBOX_SZ   = (size_t)B * 4096 * 16;    // sorted offset boxes
constexpr size_t HIST_OFF   = SOBOX_OFF + SOBOX_SZ;
constexpr size_t HIST_SZ    = (size_t)B * NBINS * 4;
constexpr size_t CNT_OFF    = HIST_OFF + HIST_SZ;
constexpr size_t CNT_SZ     = 64;
constexpr size_t SALIVE_OFF = CNT_OFF + CNT_SZ;
constexpr size_t SALIVE_SZ  = (size_t)B * 4096;
constexpr size_t THR_OFF    = SALIVE_OFF + SALIVE_SZ;
}

// ---------------- Pass 1: histogram (LDS-staged, coalesced) ----------------
__global__ __launch_bounds__(256) void k_hist(const float* __restrict__ pred,
                                              int* __restrict__ hist) {
#pragma clang fp contract(off)
  __shared__ float tile[64 * ROW];
  __shared__ int lh[NBINS];
  for (int i = threadIdx.x; i < NBINS; i += 256) lh[i] = 0;
  const int img = blockIdx.y;
  const int r0 = blockIdx.x * 64;
  const int rows = min(64, N - r0);          // 64 or 48 (both %4==0)
  const int nf4 = rows * ROW / 4;
  const float4* src = (const float4*)(pred + ((size_t)img * N + r0) * ROW);
  for (int i = threadIdx.x; i < nf4; i += 256) ((float4*)tile)[i] = src[i];
  __syncthreads();
  const int row = threadIdx.x >> 2;
  if (row < rows) {
    const float* tr = tile + row * ROW;
    const float obj = tr[4];
    const int c0 = (threadIdx.x & 3) * 20;
    for (int c = c0; c < c0 + 20; ++c) {
      float s = obj * tr[5 + c];
      if (s > CONF) {
        uint32_t b = (__float_as_uint(s) - BIN_BASE) >> 12;
        if (b > NBINS - 1) b = NBINS - 1;
        atomicAdd(&lh[b], 1);
      }
    }
  }
  __syncthreads();
  int* gh = hist + (size_t)img * NBINS;
  for (int i = threadIdx.x; i < NBINS; i += 256) {
    int v = lh[i];
    if (v) atomicAdd(&gh[i], v);
  }
}

// ---------------- Pass 2: pivot threshold per image ----------------
__global__ __launch_bounds__(256) void k_pivot(const int* __restrict__ hist,
                                               float* __restrict__ thr) {
  __shared__ int psum[256];
  const int img = blockIdx.x;
  const int* gh = hist + (size_t)img * NBINS;
  const int t = threadIdx.x;
  constexpr int CH = NBINS / 256;  // 17
  int s = 0;
  for (int b = t * CH; b < t * CH + CH; ++b) s += gh[b];
  psum[t] = s;
  __syncthreads();
  if (t == 0) {
    int cum = 0, bstar = 0;
    bool found = false;
    for (int c = 255; c >= 0 && !found; --c) {
      if (cum + psum[c] >= KSEL) {
        for (int b = c * CH + CH - 1; b >= c * CH; --b) {
          cum += gh[b];
          if (cum >= KSEL) { bstar = b; found = true; break; }
        }
      } else {
        cum += psum[c];
      }
    }
    thr[img] = __uint_as_float(BIN_BASE + ((uint32_t)bstar << 12));
  }
}

// ---------------- Pass 3: compact key records (LDS-staged) ----------------
__global__ __launch_bounds__(256) void k_compact(const float* __restrict__ pred,
                                                 const float* __restrict__ thr,
                                                 int* __restrict__ cnt,
                                                 u64* __restrict__ crec) {
#pragma clang fp contract(off)
  __shared__ float tile[64 * ROW];
  const int img = blockIdx.y;
  const int r0 = blockIdx.x * 64;
  const int rows = min(64, N - r0);
  const int nf4 = rows * ROW / 4;
  const float4* src = (const float4*)(pred + ((size_t)img * N + r0) * ROW);
  for (int i = threadIdx.x; i < nf4; i += 256) ((float4*)tile)[i] = src[i];
  __syncthreads();
  const float th = thr[img];
  const int row = threadIdx.x >> 2;
  if (row < rows) {
    const float* tr = tile + row * ROW;
    const float obj = tr[4];
    const int c0 = (threadIdx.x & 3) * 20;
    for (int c = c0; c < c0 + 20; ++c) {
      float s = obj * tr[5 + c];
      if (s > CONF && s >= th) {
        int pos = atomicAdd(&cnt[img], 1);
        if (pos < CAP) {
          uint32_t fidx = (uint32_t)(r0 + row) * NC + c;
          crec[(size_t)img * CAP + pos] =
              ((u64)__float_as_uint(s) << 32) | (u64)(uint32_t)(~fidx);
        }
      }
    }
  }
}

// ---------------- Pass 4: per-image bitonic sort (desc by key) ----------------
__global__ __launch_bounds__(1024) void k_sort(const int* __restrict__ cnt,
                                               const u64* __restrict__ crec,
                                               u64* __restrict__ skey) {
  __shared__ u64 sk[8192];
  const int img = blockIdx.x;
  const int n = min(cnt[img], CAP);
  for (int i = threadIdx.x; i < 8192; i += 1024)
    sk[i] = (i < n) ? crec[(size_t)img * CAP + i] : 0ull;
  __syncthreads();
  for (int size = 2; size <= 8192; size <<= 1) {
    for (int stride = size >> 1; stride > 0; stride >>= 1) {
      for (int j = 0; j < 4; ++j) {
        int p = threadIdx.x + (j << 10);
        int low = p & (stride - 1);
        int i1 = ((p - low) << 1) | low;
        int i2 = i1 + stride;
        u64 a = sk[i1], b = sk[i2];
        bool desc = (i1 & size) == 0;
        if (desc ? (a < b) : (a > b)) { sk[i1] = b; sk[i2] = a; }
      }
      __syncthreads();
    }
  }
  for (int i = threadIdx.x; i < 4096; i += 1024)
    skey[(size_t)img * 4096 + i] = sk[i];
}

// ---------------- Pass 5: materialize sorted offset boxes ----------------
__global__ __launch_bounds__(256) void k_mat(const float* __restrict__ pred,
                                             const u64* __restrict__ skey,
                                             float4* __restrict__ sobox) {
#pragma clang fp contract(off)
  const int img = blockIdx.y;
  const int r = blockIdx.x * 256 + threadIdx.x;
  const u64 key = skey[(size_t)img * 4096 + r];
  float4 ob = make_float4(0.f, 0.f, 0.f, 0.f);
  if (key != 0ull) {
    const uint32_t f = ~(uint32_t)key;
    const uint32_t a = f / 80u;
    const uint32_t c = f - a * 80u;
    const float* p = pred + ((size_t)img * N + a) * ROW;
    const float cx = p[0], cy = p[1], w = p[2], h = p[3];
    const float hw = w * 0.5f, hh = h * 0.5f;
    const float off = (float)c * MAX_WH;
    ob = make_float4((cx - hw) + off, (cy - hh) + off,
                     (cx + hw) + off, (cy + hh) + off);
  }
  sobox[(size_t)img * 4096 + r] = ob;
}

// ---------------- Pass 6: per-class greedy NMS (one wave per class) ----------------
__device__ __forceinline__ bool iou_gt(float4 bb, float ab, float4 bu) {
#pragma clang fp contract(off)
  float au = (bu.z - bu.x) * (bu.w - bu.y);
  float ltx = fmaxf(bb.x, bu.x), lty = fmaxf(bb.y, bu.y);
  float rbx = fminf(bb.z, bu.z), rby = fminf(bb.w, bu.w);
  float ww = fmaxf(rbx - ltx, 0.f), hh = fmaxf(rby - lty, 0.f);
  float inter = ww * hh;
  float iou = inter / (((ab + au) - inter) + 1e-7f);
  return iou > IOU_T;
}

__global__ __launch_bounds__(256) void k_cnms(const u64* __restrict__ skey,
                                              const float4* __restrict__ sobox,
                                              uint8_t* __restrict__ salive) {
#pragma clang fp contract(off)
  __shared__ uint16_t mlist[4][CAPM];
  __shared__ float4   mbox[4][CAPM];
  __shared__ uint8_t  alive[4096];
  const int img = blockIdx.y;
  const int w = threadIdx.x >> 6;
  const int lane = threadIdx.x & 63;
  const uint32_t cls = (uint32_t)(blockIdx.x * 4 + w);
  const u64* KEY = skey + (size_t)img * 4096;
  const float4* BOX = sobox + (size_t)img * 4096;

  for (int i = threadIdx.x; i < 4096; i += 256) alive[i] = 1;
  __syncthreads();

  // phase 1: collect member ranks (rank order preserved)
  int k = 0;
  for (int base = 0; base < 4096; base += 64) {
    int r = base + lane;
    u64 key = KEY[r];
    bool member = false;
    if (key != 0ull) {
      uint32_t f = ~(uint32_t)key;
      member = (f % 80u) == cls;
    }
    unsigned long long m = __ballot(member);
    if (member) {
      int pos = k + __popcll(m & ((1ull << lane) - 1ull));
      if (pos < CAPM) mlist[w][pos] = (uint16_t)r;
    }
    k += __popcll(m);
  }
  __builtin_amdgcn_wave_barrier();

  if (k <= CAPM) {
    // phase 2: cache member boxes
    for (int mm = lane; mm < k; mm += 64) mbox[w][mm] = BOX[mlist[w][mm]];
    __builtin_amdgcn_wave_barrier();
    // phase 3: greedy
    for (int t = 0; t < k; ++t) {
      int rt = mlist[w][t];
      if (!alive[rt]) continue;
      float4 bb = mbox[w][t];
      float ab = (bb.z - bb.x) * (bb.w - bb.y);
      for (int u = t + 1 + lane; u < k; u += 64) {
        int ru = mlist[w][u];
        if (!alive[ru]) continue;
        if (iou_gt(bb, ab, mbox[w][u])) alive[ru] = 0;
      }
    }
  } else {
    // generic fallback (never expected for this data): scan-based greedy
    for (int base = 0; base < 4096; base += 64) {
      int r = base + lane;
      u64 key = KEY[r];
      bool member = false;
      if (key != 0ull) member = ((~(uint32_t)key) % 80u) == cls;
      unsigned long long m = __ballot(member);
      while (m) {
        int l = __builtin_ctzll(m);
        m &= m - 1;
        int rt = base + l;
        if (!alive[rt]) continue;
        float4 bb = BOX[rt];
        float ab = (bb.z - bb.x) * (bb.w - bb.y);
        for (int b2 = base; b2 < 4096; b2 += 64) {
          int r2 = b2 + lane;
          if (r2 <= rt) continue;
          u64 k2 = KEY[r2];
          if (k2 == 0ull) continue;
          if (((~(uint32_t)k2) % 80u) != cls) continue;
          if (!alive[r2]) continue;
          if (iou_gt(bb, ab, BOX[r2])) alive[r2] = 0;
        }
      }
    }
  }
  __builtin_amdgcn_wave_barrier();

  // write survivor flags for this class's ranks
  uint8_t* sag = salive + (size_t)img * 4096;
  for (int base = 0; base < 4096; base += 64) {
    int r = base + lane;
    u64 key = KEY[r];
    if (key != 0ull) {
      if (((~(uint32_t)key) % 80u) == cls) sag[r] = alive[r];
    }
  }
}

// ---------------- Pass 7: prefix over survivors, emit top-300 ----------------
__global__ __launch_bounds__(1024) void k_out(const float* __restrict__ pred,
                                              const u64* __restrict__ skey,
                                              const uint8_t* __restrict__ salive,
                                              float* __restrict__ out) {
#pragma clang fp contract(off)
  __shared__ uint32_t ps[1024];
  __shared__ uint32_t stot;
  const int img = blockIdx.x;
  const int tid = threadIdx.x;
  const uint8_t* sag = salive + (size_t)img * 4096;
  int fl[4];
  int s4 = 0;
  for (int j = 0; j < 4; ++j) { fl[j] = sag[tid * 4 + j]; s4 += fl[j]; }
  ps[tid] = (uint32_t)s4;
  __syncthreads();
  for (int d = 1; d < 1024; d <<= 1) {
    uint32_t v = (tid >= d) ? ps[tid - d] : 0u;
    __syncthreads();
    ps[tid] += v;
    __syncthreads();
  }
  if (tid == 1023) stot = ps[1023];
  __syncthreads();
  uint32_t off = ps[tid] - (uint32_t)s4;  // exclusive prefix
  for (int j = 0; j < 4; ++j) {
    if (fl[j]) {
      if (off < MAX_DET) {
        int rank = tid * 4 + j;
        u64 key = skey[(size_t)img * 4096 + rank];
        uint32_t f = ~(uint32_t)key;
        uint32_t a = f / 80u;
        uint32_t cc = f - a * 80u;
        const float* p = pred + ((size_t)img * N + a) * ROW;
        float cx = p[0], cy = p[1], w = p[2], h = p[3];
        float hw = w * 0.5f, hh = h * 0.5f;
        float* o = out + ((size_t)img * MAX_DET + off) * 6;
        o[0] = cx - hw;
        o[1] = cy - hh;
        o[2] = cx + hw;
        o[3] = cy + hh;
        o[4] = __uint_as_float((uint32_t)(key >> 32));
        o[5] = (float)cc;
      }
      off++;
    }
  }
  uint32_t total = stot;
  if (total > MAX_DET) total = MAX_DET;
  for (int i = (int)total + tid; i < MAX_DET; i += 1024) {
    float* o = out + ((size_t)img * MAX_DET + i) * 6;
    o[0] = 0.f; o[1] = 0.f; o[2] = 0.f; o[3] = 0.f; o[4] = 0.f; o[5] = 0.f;
  }
}

extern "C" void kernel_launch(void* const* d_in, const int* in_sizes, int n_in,
                              void* d_out, int out_size, void* d_ws, size_t ws_size,
                              hipStream_t stream) {
  const float* pred = (const float*)d_in[0];
  float* out = (float*)d_out;
  char* ws = (char*)d_ws;

  u64*     crec   = (u64*)(ws + CREC_OFF);
  u64*     skey   = (u64*)(ws + SKEY_OFF);
  float4*  sobox  = (float4*)(ws + SOBOX_OFF);
  int*     hist   = (int*)(ws + HIST_OFF);
  int*     cnt    = (int*)(ws + CNT_OFF);
  uint8_t* salive = (uint8_t*)(ws + SALIVE_OFF);
  float*   thr    = (float*)(ws + THR_OFF);

  hipMemsetAsync(hist, 0, HIST_SZ + CNT_SZ, stream);
  hipMemsetAsync(salive, 0, SALIVE_SZ, stream);

  dim3 gbulk((N + 63) / 64, B);
  k_hist<<<gbulk, 256, 0, stream>>>(pred, hist);
  k_pivot<<<B, 256, 0, stream>>>(hist, thr);
  k_compact<<<gbulk, 256, 0, stream>>>(pred, thr, cnt, crec);
  k_sort<<<B, 1024, 0, stream>>>(cnt, crec, skey);
  dim3 gmat(16, B);
  k_mat<<<gmat, 256, 0, stream>>>(pred, skey, sobox);
  dim3 gnms(NC / 4, B);
  k_cnms<<<gnms, 256, 0, stream>>>(skey, sobox, salive);
  k_out<<<B, 1024, 0, stream>>>(pred, skey, salive, out);
}

// Round 3
// 593.605 us; speedup vs baseline: 3.5066x; 1.5463x over previous
//
#include <hip/hip_runtime.h>
#include <stdint.h>

namespace {
typedef unsigned long long u64;
constexpr int B    = 16;
constexpr int N    = 25200;
constexpr int NC   = 80;
constexpr int ROW  = 85;
constexpr float CONF  = 0.25f;
constexpr float IOU_T = 0.45f;
constexpr float MAX_WH = 7680.0f;
constexpr int MAX_DET = 300;
constexpr int KSEL = 4096;
constexpr int CAP  = 6144;          // candidate capacity per image
constexpr int CAPM = 448;           // per-class member fast-path capacity
constexpr int NBINS = 4352;
constexpr uint32_t BIN_BASE = 0x3E800000u;  // bits(0.25f)

// ws layout (bytes), all 16B-aligned
constexpr size_t CREC_OFF   = 0;
constexpr size_t CREC_SZ    = (size_t)B * CAP * 8;      // u64 key records
constexpr size_t SKEY_OFF   = CREC_OFF + CREC_SZ;
constexpr size_t SKEY_SZ    = (size_t)B * 4096 * 8;     // sorted keys (top 4096)
constexpr size_t SOBOX_OFF  = SKEY_OFF + SKEY_SZ;
constexpr size_t SOBOX_SZ   = (size_t)B * 4096 * 16;    // sorted offset boxes
constexpr size_t HIST_OFF   = SOBOX_OFF + SOBOX_SZ;
constexpr size_t HIST_SZ    = (size_t)B * NBINS * 4;    // layout [bin][B] (transposed)
constexpr size_t CNT_OFF    = HIST_OFF + HIST_SZ;
constexpr size_t CNT_SZ     = (size_t)B * 32 * 4;       // one 128B line per image
constexpr size_t SALIVE_OFF = CNT_OFF + CNT_SZ;
constexpr size_t SALIVE_SZ  = (size_t)B * 4096;
constexpr size_t THR_OFF    = SALIVE_OFF + SALIVE_SZ;
}

// ---------------- Pass 1: histogram (LDS-staged, coalesced) ----------------
__global__ __launch_bounds__(256) void k_hist(const float* __restrict__ pred,
                                              int* __restrict__ hist) {
#pragma clang fp contract(off)
  __shared__ float tile[64 * ROW];
  __shared__ int lh[NBINS];
  for (int i = threadIdx.x; i < NBINS; i += 256) lh[i] = 0;
  const int img = blockIdx.y;
  const int r0 = blockIdx.x * 64;
  const int rows = min(64, N - r0);          // 64 or 48 (both %4==0)
  const int nf4 = rows * ROW / 4;
  const float4* src = (const float4*)(pred + ((size_t)img * N + r0) * ROW);
  for (int i = threadIdx.x; i < nf4; i += 256) ((float4*)tile)[i] = src[i];
  __syncthreads();
  const int row = threadIdx.x >> 2;
  if (row < rows) {
    const float* tr = tile + row * ROW;
    const float obj = tr[4];
    const int c0 = (threadIdx.x & 3) * 20;
    for (int c = c0; c < c0 + 20; ++c) {
      float s = obj * tr[5 + c];
      if (s > CONF) {
        uint32_t b = (__float_as_uint(s) - BIN_BASE) >> 12;
        if (b > NBINS - 1) b = NBINS - 1;
        atomicAdd(&lh[b], 1);
      }
    }
  }
  __syncthreads();
  // transposed flush: hist[bin*B + img] — spreads each image's atomics
  // over ~2176 cachelines instead of 136 (cross-XCD line bounce relief)
  for (int i = threadIdx.x; i < NBINS; i += 256) {
    int v = lh[i];
    if (v) atomicAdd(&hist[(size_t)i * B + img], v);
  }
}

// ---------------- Pass 2: pivot threshold per image ----------------
__global__ __launch_bounds__(256) void k_pivot(const int* __restrict__ hist,
                                               float* __restrict__ thr) {
  __shared__ int psum[256];
  __shared__ int gh[NBINS];
  const int img = blockIdx.x;
  const int t = threadIdx.x;
  for (int b = t; b < NBINS; b += 256) gh[b] = hist[(size_t)b * B + img];
  __syncthreads();
  constexpr int CH = NBINS / 256;  // 17
  int s = 0;
  for (int b = t * CH; b < t * CH + CH; ++b) s += gh[b];
  psum[t] = s;
  __syncthreads();
  if (t == 0) {
    int cum = 0, bstar = 0;
    bool found = false;
    for (int c = 255; c >= 0 && !found; --c) {
      if (cum + psum[c] >= KSEL) {
        for (int b = c * CH + CH - 1; b >= c * CH; --b) {
          cum += gh[b];
          if (cum >= KSEL) { bstar = b; found = true; break; }
        }
      } else {
        cum += psum[c];
      }
    }
    thr[img] = __uint_as_float(BIN_BASE + ((uint32_t)bstar << 12));
  }
}

// ---------------- Pass 3: compact key records (block-aggregated atomic) -----
__global__ __launch_bounds__(256) void k_compact(const float* __restrict__ pred,
                                                 const float* __restrict__ thr,
                                                 int* __restrict__ cnt,
                                                 u64* __restrict__ crec) {
#pragma clang fp contract(off)
  __shared__ float tile[64 * ROW];
  __shared__ int blkcnt;
  __shared__ int blkbase;
  const int img = blockIdx.y;
  const int r0 = blockIdx.x * 64;
  const int rows = min(64, N - r0);
  const int nf4 = rows * ROW / 4;
  const float4* src = (const float4*)(pred + ((size_t)img * N + r0) * ROW);
  for (int i = threadIdx.x; i < nf4; i += 256) ((float4*)tile)[i] = src[i];
  if (threadIdx.x == 0) blkcnt = 0;
  __syncthreads();
  const float th = thr[img];
  const int row = threadIdx.x >> 2;
  const int c0 = (threadIdx.x & 3) * 20;
  uint32_t mask = 0;
  int loc = 0;
  if (row < rows) {
    const float* tr = tile + row * ROW;
    const float obj = tr[4];
    for (int j = 0; j < 20; ++j) {
      float s = obj * tr[5 + c0 + j];
      if (s > CONF && s >= th) mask |= (1u << j);
    }
    int c = __popc(mask);
    if (c) loc = atomicAdd(&blkcnt, c);   // LDS atomic: cheap
  }
  __syncthreads();
  if (threadIdx.x == 0) blkbase = atomicAdd(&cnt[img * 32], blkcnt);  // 1/block
  __syncthreads();
  if (mask) {
    const float* tr = tile + row * ROW;
    const float obj = tr[4];
    int pos = blkbase + loc;
    uint32_t m = mask;
    while (m) {
      int j = __builtin_ctz(m);
      m &= m - 1;
      int c = c0 + j;
      float s = obj * tr[5 + c];
      if (pos < CAP) {
        uint32_t fidx = (uint32_t)(r0 + row) * NC + c;
        crec[(size_t)img * CAP + pos] =
            ((u64)__float_as_uint(s) << 32) | (u64)(uint32_t)(~fidx);
      }
      pos++;
    }
  }
}

// ---------------- Pass 4: per-image bitonic sort (desc by key) ----------------
__global__ __launch_bounds__(1024) void k_sort(const int* __restrict__ cnt,
                                               const u64* __restrict__ crec,
                                               u64* __restrict__ skey) {
  __shared__ u64 sk[8192];
  const int img = blockIdx.x;
  const int n = min(cnt[img * 32], CAP);
  for (int i = threadIdx.x; i < 8192; i += 1024)
    sk[i] = (i < n) ? crec[(size_t)img * CAP + i] : 0ull;
  __syncthreads();
  for (int size = 2; size <= 8192; size <<= 1) {
    for (int stride = size >> 1; stride > 0; stride >>= 1) {
      for (int j = 0; j < 4; ++j) {
        int p = threadIdx.x + (j << 10);
        int low = p & (stride - 1);
        int i1 = ((p - low) << 1) | low;
        int i2 = i1 + stride;
        u64 a = sk[i1], b = sk[i2];
        bool desc = (i1 & size) == 0;
        if (desc ? (a < b) : (a > b)) { sk[i1] = b; sk[i2] = a; }
      }
      __syncthreads();
    }
  }
  for (int i = threadIdx.x; i < 4096; i += 1024)
    skey[(size_t)img * 4096 + i] = sk[i];
}

// ---------------- Pass 5: materialize sorted offset boxes ----------------
__global__ __launch_bounds__(256) void k_mat(const float* __restrict__ pred,
                                             const u64* __restrict__ skey,
                                             float4* __restrict__ sobox) {
#pragma clang fp contract(off)
  const int img = blockIdx.y;
  const int r = blockIdx.x * 256 + threadIdx.x;
  const u64 key = skey[(size_t)img * 4096 + r];
  float4 ob = make_float4(0.f, 0.f, 0.f, 0.f);
  if (key != 0ull) {
    const uint32_t f = ~(uint32_t)key;
    const uint32_t a = f / 80u;
    const uint32_t c = f - a * 80u;
    const float* p = pred + ((size_t)img * N + a) * ROW;
    const float cx = p[0], cy = p[1], w = p[2], h = p[3];
    const float hw = w * 0.5f, hh = h * 0.5f;
    const float off = (float)c * MAX_WH;
    ob = make_float4((cx - hw) + off, (cy - hh) + off,
                     (cx + hw) + off, (cy + hh) + off);
  }
  sobox[(size_t)img * 4096 + r] = ob;
}

// ---------------- Pass 6: per-class greedy NMS (one wave per class) ----------------
__device__ __forceinline__ bool iou_gt(float4 bb, float ab, float4 bu) {
#pragma clang fp contract(off)
  float au = (bu.z - bu.x) * (bu.w - bu.y);
  float ltx = fmaxf(bb.x, bu.x), lty = fmaxf(bb.y, bu.y);
  float rbx = fminf(bb.z, bu.z), rby = fminf(bb.w, bu.w);
  float ww = fmaxf(rbx - ltx, 0.f), hh = fmaxf(rby - lty, 0.f);
  float inter = ww * hh;
  float iou = inter / (((ab + au) - inter) + 1e-7f);
  return iou > IOU_T;
}

__global__ __launch_bounds__(256) void k_cnms(const u64* __restrict__ skey,
                                              const float4* __restrict__ sobox,
                                              uint8_t* __restrict__ salive) {
#pragma clang fp contract(off)
  __shared__ uint16_t mlist[4][CAPM];
  __shared__ float4   mbox[4][CAPM];
  __shared__ uint8_t  alive[4096];
  const int img = blockIdx.y;
  const int w = threadIdx.x >> 6;
  const int lane = threadIdx.x & 63;
  const uint32_t cls = (uint32_t)(blockIdx.x * 4 + w);
  const u64* KEY = skey + (size_t)img * 4096;
  const float4* BOX = sobox + (size_t)img * 4096;

  for (int i = threadIdx.x; i < 4096; i += 256) alive[i] = 1;
  __syncthreads();

  // phase 1: collect member ranks (rank order preserved)
  int k = 0;
  for (int base = 0; base < 4096; base += 64) {
    int r = base + lane;
    u64 key = KEY[r];
    bool member = false;
    if (key != 0ull) {
      uint32_t f = ~(uint32_t)key;
      member = (f % 80u) == cls;
    }
    unsigned long long m = __ballot(member);
    if (member) {
      int pos = k + __popcll(m & ((1ull << lane) - 1ull));
      if (pos < CAPM) mlist[w][pos] = (uint16_t)r;
    }
    k += __popcll(m);
  }
  __builtin_amdgcn_wave_barrier();

  if (k <= CAPM) {
    // phase 2: cache member boxes
    for (int mm = lane; mm < k; mm += 64) mbox[w][mm] = BOX[mlist[w][mm]];
    __builtin_amdgcn_wave_barrier();
    // phase 3: greedy
    for (int t = 0; t < k; ++t) {
      int rt = mlist[w][t];
      if (!alive[rt]) continue;
      float4 bb = mbox[w][t];
      float ab = (bb.z - bb.x) * (bb.w - bb.y);
      for (int u = t + 1 + lane; u < k; u += 64) {
        int ru = mlist[w][u];
        if (!alive[ru]) continue;
        if (iou_gt(bb, ab, mbox[w][u])) alive[ru] = 0;
      }
    }
  } else {
    // generic fallback (never expected for this data): scan-based greedy
    for (int base = 0; base < 4096; base += 64) {
      int r = base + lane;
      u64 key = KEY[r];
      bool member = false;
      if (key != 0ull) member = ((~(uint32_t)key) % 80u) == cls;
      unsigned long long m = __ballot(member);
      while (m) {
        int l = __builtin_ctzll(m);
        m &= m - 1;
        int rt = base + l;
        if (!alive[rt]) continue;
        float4 bb = BOX[rt];
        float ab = (bb.z - bb.x) * (bb.w - bb.y);
        for (int b2 = base; b2 < 4096; b2 += 64) {
          int r2 = b2 + lane;
          if (r2 <= rt) continue;
          u64 k2 = KEY[r2];
          if (k2 == 0ull) continue;
          if (((~(uint32_t)k2) % 80u) != cls) continue;
          if (!alive[r2]) continue;
          if (iou_gt(bb, ab, BOX[r2])) alive[r2] = 0;
        }
      }
    }
  }
  __builtin_amdgcn_wave_barrier();

  // write survivor flags for this class's ranks
  uint8_t* sag = salive + (size_t)img * 4096;
  for (int base = 0; base < 4096; base += 64) {
    int r = base + lane;
    u64 key = KEY[r];
    if (key != 0ull) {
      if (((~(uint32_t)key) % 80u) == cls) sag[r] = alive[r];
    }
  }
}

// ---------------- Pass 7: prefix over survivors, emit top-300 ----------------
__global__ __launch_bounds__(1024) void k_out(const float* __restrict__ pred,
                                              const u64* __restrict__ skey,
                                              const uint8_t* __restrict__ salive,
                                              float* __restrict__ out) {
#pragma clang fp contract(off)
  __shared__ uint32_t ps[1024];
  __shared__ uint32_t stot;
  const int img = blockIdx.x;
  const int tid = threadIdx.x;
  const uint8_t* sag = salive + (size_t)img * 4096;
  int fl[4];
  int s4 = 0;
  for (int j = 0; j < 4; ++j) { fl[j] = sag[tid * 4 + j]; s4 += fl[j]; }
  ps[tid] = (uint32_t)s4;
  __syncthreads();
  for (int d = 1; d < 1024; d <<= 1) {
    uint32_t v = (tid >= d) ? ps[tid - d] : 0u;
    __syncthreads();
    ps[tid] += v;
    __syncthreads();
  }
  if (tid == 1023) stot = ps[1023];
  __syncthreads();
  uint32_t off = ps[tid] - (uint32_t)s4;  // exclusive prefix
  for (int j = 0; j < 4; ++j) {
    if (fl[j]) {
      if (off < MAX_DET) {
        int rank = tid * 4 + j;
        u64 key = skey[(size_t)img * 4096 + rank];
        uint32_t f = ~(uint32_t)key;
        uint32_t a = f / 80u;
        uint32_t cc = f - a * 80u;
        const float* p = pred + ((size_t)img * N + a) * ROW;
        float cx = p[0], cy = p[1], w = p[2], h = p[3];
        float hw = w * 0.5f, hh = h * 0.5f;
        float* o = out + ((size_t)img * MAX_DET + off) * 6;
        o[0] = cx - hw;
        o[1] = cy - hh;
        o[2] = cx + hw;
        o[3] = cy + hh;
        o[4] = __uint_as_float((uint32_t)(key >> 32));
        o[5] = (float)cc;
      }
      off++;
    }
  }
  uint32_t total = stot;
  if (total > MAX_DET) total = MAX_DET;
  for (int i = (int)total + tid; i < MAX_DET; i += 1024) {
    float* o = out + ((size_t)img * MAX_DET + i) * 6;
    o[0] = 0.f; o[1] = 0.f; o[2] = 0.f; o[3] = 0.f; o[4] = 0.f; o[5] = 0.f;
  }
}

extern "C" void kernel_launch(void* const* d_in, const int* in_sizes, int n_in,
                              void* d_out, int out_size, void* d_ws, size_t ws_size,
                              hipStream_t stream) {
  const float* pred = (const float*)d_in[0];
  float* out = (float*)d_out;
  char* ws = (char*)d_ws;

  u64*     crec   = (u64*)(ws + CREC_OFF);
  u64*     skey   = (u64*)(ws + SKEY_OFF);
  float4*  sobox  = (float4*)(ws + SOBOX_OFF);
  int*     hist   = (int*)(ws + HIST_OFF);
  int*     cnt    = (int*)(ws + CNT_OFF);
  uint8_t* salive = (uint8_t*)(ws + SALIVE_OFF);
  float*   thr    = (float*)(ws + THR_OFF);

  hipMemsetAsync(hist, 0, HIST_SZ + CNT_SZ, stream);
  hipMemsetAsync(salive, 0, SALIVE_SZ, stream);

  dim3 gbulk((N + 63) / 64, B);
  k_hist<<<gbulk, 256, 0, stream>>>(pred, hist);
  k_pivot<<<B, 256, 0, stream>>>(hist, thr);
  k_compact<<<gbulk, 256, 0, stream>>>(pred, thr, cnt, crec);
  k_sort<<<B, 1024, 0, stream>>>(cnt, crec, skey);
  dim3 gmat(16, B);
  k_mat<<<gmat, 256, 0, stream>>>(pred, skey, sobox);
  dim3 gnms(NC / 4, B);
  k_cnms<<<gnms, 256, 0, stream>>>(skey, sobox, salive);
  k_out<<<B, 1024, 0, stream>>>(pred, skey, salive, out);
}

// Round 4
// 268.019 us; speedup vs baseline: 7.7664x; 2.2148x over previous
//
#include <hip/hip_runtime.h>
#include <stdint.h>

namespace {
typedef unsigned long long u64;
constexpr int B    = 16;
constexpr int N    = 25200;
constexpr int NC   = 80;
constexpr int ROW  = 85;
constexpr float CONF  = 0.25f;
constexpr float IOU_T = 0.45f;
constexpr float MAX_WH = 7680.0f;
constexpr int MAX_DET = 300;
constexpr int KSEL = 4096;
constexpr int CAP  = 6144;          // candidate capacity per image
constexpr int CAPM = 448;           // per-class member fast-path capacity
constexpr int NBINS = 4352;
constexpr int NCOPY = 8;            // one histogram copy per XCD
constexpr uint32_t BIN_BASE = 0x3E800000u;  // bits(0.25f)

// ws layout (bytes), all 16B-aligned
constexpr size_t CREC_OFF   = 0;
constexpr size_t CREC_SZ    = (size_t)B * CAP * 8;      // u64 key records
constexpr size_t SKEY_OFF   = CREC_OFF + CREC_SZ;
constexpr size_t SKEY_SZ    = (size_t)B * 4096 * 8;     // sorted keys (top 4096)
constexpr size_t SOBOX_OFF  = SKEY_OFF + SKEY_SZ;
constexpr size_t SOBOX_SZ   = (size_t)B * 4096 * 16;    // sorted offset boxes
constexpr size_t HIST_OFF   = SOBOX_OFF + SOBOX_SZ;
constexpr size_t HIST_SZ    = (size_t)NCOPY * B * NBINS * 4;  // [copy][img][bin]
constexpr size_t CNT_OFF    = HIST_OFF + HIST_SZ;
constexpr size_t CNT_SZ     = (size_t)B * 32 * 4;       // one 128B line per image
constexpr size_t SALIVE_OFF = CNT_OFF + CNT_SZ;
constexpr size_t SALIVE_SZ  = (size_t)B * 4096;
constexpr size_t THR_OFF    = SALIVE_OFF + SALIVE_SZ;
}

// ---------------- Pass 1: histogram (LDS-staged, XCD-local merge) ----------------
__global__ __launch_bounds__(256) void k_hist(const float* __restrict__ pred,
                                              int* __restrict__ hist) {
#pragma clang fp contract(off)
  __shared__ float tile[64 * ROW];
  __shared__ int lh[NBINS];
  for (int i = threadIdx.x; i < NBINS; i += 256) lh[i] = 0;
  const int img = blockIdx.y;
  const int r0 = blockIdx.x * 64;
  const int rows = min(64, N - r0);          // 64 or 48 (both %4==0)
  const int nf4 = rows * ROW / 4;
  const float4* src = (const float4*)(pred + ((size_t)img * N + r0) * ROW);
  for (int i = threadIdx.x; i < nf4; i += 256) ((float4*)tile)[i] = src[i];
  __syncthreads();
  const int row = threadIdx.x >> 2;
  if (row < rows) {
    const float* tr = tile + row * ROW;
    const float obj = tr[4];
    const int c0 = (threadIdx.x & 3) * 20;
    for (int c = c0; c < c0 + 20; ++c) {
      float s = obj * tr[5 + c];
      if (s > CONF) {
        uint32_t b = (__float_as_uint(s) - BIN_BASE) >> 12;
        if (b > NBINS - 1) b = NBINS - 1;
        atomicAdd(&lh[b], 1);
      }
    }
  }
  __syncthreads();
  // XCD-local flush: workgroups round-robin across the 8 XCDs by linear id,
  // so copy = linear&7 keeps each copy's cachelines in ONE XCD's L2 —
  // no cross-XCD line bounces (that was 416us of round 3).
  const int copy = (blockIdx.y * gridDim.x + blockIdx.x) & (NCOPY - 1);
  int* gh = hist + ((size_t)copy * B + img) * NBINS;
  for (int i = threadIdx.x; i < NBINS; i += 256) {
    int v = lh[i];
    if (v) atomicAdd(&gh[i], v);
  }
}

// ---------------- Pass 2: pivot threshold per image (sum 8 copies) ----------------
__global__ __launch_bounds__(256) void k_pivot(const int* __restrict__ hist,
                                               float* __restrict__ thr) {
  __shared__ int psum[256];
  __shared__ int gh[NBINS];
  const int img = blockIdx.x;
  const int t = threadIdx.x;
  for (int b = t; b < NBINS; b += 256) {
    int s = 0;
    for (int c = 0; c < NCOPY; ++c)
      s += hist[((size_t)c * B + img) * NBINS + b];
    gh[b] = s;
  }
  __syncthreads();
  constexpr int CH = NBINS / 256;  // 17
  int s = 0;
  for (int b = t * CH; b < t * CH + CH; ++b) s += gh[b];
  psum[t] = s;
  __syncthreads();
  if (t == 0) {
    int cum = 0, bstar = 0;
    bool found = false;
    for (int c = 255; c >= 0 && !found; --c) {
      if (cum + psum[c] >= KSEL) {
        for (int b = c * CH + CH - 1; b >= c * CH; --b) {
          cum += gh[b];
          if (cum >= KSEL) { bstar = b; found = true; break; }
        }
      } else {
        cum += psum[c];
      }
    }
    thr[img] = __uint_as_float(BIN_BASE + ((uint32_t)bstar << 12));
  }
}

// ---------------- Pass 3: compact key records (block-aggregated atomic) -----
__global__ __launch_bounds__(256) void k_compact(const float* __restrict__ pred,
                                                 const float* __restrict__ thr,
                                                 int* __restrict__ cnt,
                                                 u64* __restrict__ crec) {
#pragma clang fp contract(off)
  __shared__ float tile[64 * ROW];
  __shared__ int blkcnt;
  __shared__ int blkbase;
  const int img = blockIdx.y;
  const int r0 = blockIdx.x * 64;
  const int rows = min(64, N - r0);
  const int nf4 = rows * ROW / 4;
  const float4* src = (const float4*)(pred + ((size_t)img * N + r0) * ROW);
  for (int i = threadIdx.x; i < nf4; i += 256) ((float4*)tile)[i] = src[i];
  if (threadIdx.x == 0) blkcnt = 0;
  __syncthreads();
  const float th = thr[img];
  const int row = threadIdx.x >> 2;
  const int c0 = (threadIdx.x & 3) * 20;
  uint32_t mask = 0;
  int loc = 0;
  if (row < rows) {
    const float* tr = tile + row * ROW;
    const float obj = tr[4];
    for (int j = 0; j < 20; ++j) {
      float s = obj * tr[5 + c0 + j];
      if (s > CONF && s >= th) mask |= (1u << j);
    }
    int c = __popc(mask);
    if (c) loc = atomicAdd(&blkcnt, c);   // LDS atomic: cheap
  }
  __syncthreads();
  if (threadIdx.x == 0) blkbase = atomicAdd(&cnt[img * 32], blkcnt);  // 1/block
  __syncthreads();
  if (mask) {
    const float* tr = tile + row * ROW;
    const float obj = tr[4];
    int pos = blkbase + loc;
    uint32_t m = mask;
    while (m) {
      int j = __builtin_ctz(m);
      m &= m - 1;
      int c = c0 + j;
      float s = obj * tr[5 + c];
      if (pos < CAP) {
        uint32_t fidx = (uint32_t)(r0 + row) * NC + c;
        crec[(size_t)img * CAP + pos] =
            ((u64)__float_as_uint(s) << 32) | (u64)(uint32_t)(~fidx);
      }
      pos++;
    }
  }
}

// ---------------- Pass 4: per-image bitonic sort (desc by key) ----------------
__global__ __launch_bounds__(1024) void k_sort(const int* __restrict__ cnt,
                                               const u64* __restrict__ crec,
                                               u64* __restrict__ skey) {
  __shared__ u64 sk[8192];
  const int img = blockIdx.x;
  const int n = min(cnt[img * 32], CAP);
  for (int i = threadIdx.x; i < 8192; i += 1024)
    sk[i] = (i < n) ? crec[(size_t)img * CAP + i] : 0ull;
  __syncthreads();
  for (int size = 2; size <= 8192; size <<= 1) {
    for (int stride = size >> 1; stride > 0; stride >>= 1) {
      for (int j = 0; j < 4; ++j) {
        int p = threadIdx.x + (j << 10);
        int low = p & (stride - 1);
        int i1 = ((p - low) << 1) | low;
        int i2 = i1 + stride;
        u64 a = sk[i1], b = sk[i2];
        bool desc = (i1 & size) == 0;
        if (desc ? (a < b) : (a > b)) { sk[i1] = b; sk[i2] = a; }
      }
      __syncthreads();
    }
  }
  for (int i = threadIdx.x; i < 4096; i += 1024)
    skey[(size_t)img * 4096 + i] = sk[i];
}

// ---------------- Pass 5: materialize sorted offset boxes ----------------
__global__ __launch_bounds__(256) void k_mat(const float* __restrict__ pred,
                                             const u64* __restrict__ skey,
                                             float4* __restrict__ sobox) {
#pragma clang fp contract(off)
  const int img = blockIdx.y;
  const int r = blockIdx.x * 256 + threadIdx.x;
  const u64 key = skey[(size_t)img * 4096 + r];
  float4 ob = make_float4(0.f, 0.f, 0.f, 0.f);
  if (key != 0ull) {
    const uint32_t f = ~(uint32_t)key;
    const uint32_t a = f / 80u;
    const uint32_t c = f - a * 80u;
    const float* p = pred + ((size_t)img * N + a) * ROW;
    const float cx = p[0], cy = p[1], w = p[2], h = p[3];
    const float hw = w * 0.5f, hh = h * 0.5f;
    const float off = (float)c * MAX_WH;
    ob = make_float4((cx - hw) + off, (cy - hh) + off,
                     (cx + hw) + off, (cy + hh) + off);
  }
  sobox[(size_t)img * 4096 + r] = ob;
}

// ---------------- Pass 6: per-class greedy NMS (one wave per class) ----------------
__device__ __forceinline__ bool iou_gt(float4 bb, float ab, float4 bu) {
#pragma clang fp contract(off)
  float au = (bu.z - bu.x) * (bu.w - bu.y);
  float ltx = fmaxf(bb.x, bu.x), lty = fmaxf(bb.y, bu.y);
  float rbx = fminf(bb.z, bu.z), rby = fminf(bb.w, bu.w);
  float ww = fmaxf(rbx - ltx, 0.f), hh = fmaxf(rby - lty, 0.f);
  float inter = ww * hh;
  float iou = inter / (((ab + au) - inter) + 1e-7f);
  return iou > IOU_T;
}

__global__ __launch_bounds__(256) void k_cnms(const u64* __restrict__ skey,
                                              const float4* __restrict__ sobox,
                                              uint8_t* __restrict__ salive) {
#pragma clang fp contract(off)
  __shared__ uint16_t mlist[4][CAPM];
  __shared__ float4   mbox[4][CAPM];
  __shared__ uint8_t  alive[4096];
  const int img = blockIdx.y;
  const int w = threadIdx.x >> 6;
  const int lane = threadIdx.x & 63;
  const uint32_t cls = (uint32_t)(blockIdx.x * 4 + w);
  const u64* KEY = skey + (size_t)img * 4096;
  const float4* BOX = sobox + (size_t)img * 4096;

  for (int i = threadIdx.x; i < 4096; i += 256) alive[i] = 1;
  __syncthreads();

  // phase 1: collect member ranks (rank order preserved)
  int k = 0;
  for (int base = 0; base < 4096; base += 64) {
    int r = base + lane;
    u64 key = KEY[r];
    bool member = false;
    if (key != 0ull) {
      uint32_t f = ~(uint32_t)key;
      member = (f % 80u) == cls;
    }
    unsigned long long m = __ballot(member);
    if (member) {
      int pos = k + __popcll(m & ((1ull << lane) - 1ull));
      if (pos < CAPM) mlist[w][pos] = (uint16_t)r;
    }
    k += __popcll(m);
  }
  __builtin_amdgcn_wave_barrier();

  if (k <= CAPM) {
    // phase 2: cache member boxes
    for (int mm = lane; mm < k; mm += 64) mbox[w][mm] = BOX[mlist[w][mm]];
    __builtin_amdgcn_wave_barrier();
    // phase 3: greedy
    for (int t = 0; t < k; ++t) {
      int rt = mlist[w][t];
      if (!alive[rt]) continue;
      float4 bb = mbox[w][t];
      float ab = (bb.z - bb.x) * (bb.w - bb.y);
      for (int u = t + 1 + lane; u < k; u += 64) {
        int ru = mlist[w][u];
        if (!alive[ru]) continue;
        if (iou_gt(bb, ab, mbox[w][u])) alive[ru] = 0;
      }
    }
  } else {
    // generic fallback (never expected for this data): scan-based greedy
    for (int base = 0; base < 4096; base += 64) {
      int r = base + lane;
      u64 key = KEY[r];
      bool member = false;
      if (key != 0ull) member = ((~(uint32_t)key) % 80u) == cls;
      unsigned long long m = __ballot(member);
      while (m) {
        int l = __builtin_ctzll(m);
        m &= m - 1;
        int rt = base + l;
        if (!alive[rt]) continue;
        float4 bb = BOX[rt];
        float ab = (bb.z - bb.x) * (bb.w - bb.y);
        for (int b2 = base; b2 < 4096; b2 += 64) {
          int r2 = b2 + lane;
          if (r2 <= rt) continue;
          u64 k2 = KEY[r2];
          if (k2 == 0ull) continue;
          if (((~(uint32_t)k2) % 80u) != cls) continue;
          if (!alive[r2]) continue;
          if (iou_gt(bb, ab, BOX[r2])) alive[r2] = 0;
        }
      }
    }
  }
  __builtin_amdgcn_wave_barrier();

  // write survivor flags for this class's ranks
  uint8_t* sag = salive + (size_t)img * 4096;
  for (int base = 0; base < 4096; base += 64) {
    int r = base + lane;
    u64 key = KEY[r];
    if (key != 0ull) {
      if (((~(uint32_t)key) % 80u) == cls) sag[r] = alive[r];
    }
  }
}

// ---------------- Pass 7: prefix over survivors, emit top-300 ----------------
__global__ __launch_bounds__(1024) void k_out(const float* __restrict__ pred,
                                              const u64* __restrict__ skey,
                                              const uint8_t* __restrict__ salive,
                                              float* __restrict__ out) {
#pragma clang fp contract(off)
  __shared__ uint32_t ps[1024];
  __shared__ uint32_t stot;
  const int img = blockIdx.x;
  const int tid = threadIdx.x;
  const uint8_t* sag = salive + (size_t)img * 4096;
  int fl[4];
  int s4 = 0;
  for (int j = 0; j < 4; ++j) { fl[j] = sag[tid * 4 + j]; s4 += fl[j]; }
  ps[tid] = (uint32_t)s4;
  __syncthreads();
  for (int d = 1; d < 1024; d <<= 1) {
    uint32_t v = (tid >= d) ? ps[tid - d] : 0u;
    __syncthreads();
    ps[tid] += v;
    __syncthreads();
  }
  if (tid == 1023) stot = ps[1023];
  __syncthreads();
  uint32_t off = ps[tid] - (uint32_t)s4;  // exclusive prefix
  for (int j = 0; j < 4; ++j) {
    if (fl[j]) {
      if (off < MAX_DET) {
        int rank = tid * 4 + j;
        u64 key = skey[(size_t)img * 4096 + rank];
        uint32_t f = ~(uint32_t)key;
        uint32_t a = f / 80u;
        uint32_t cc = f - a * 80u;
        const float* p = pred + ((size_t)img * N + a) * ROW;
        float cx = p[0], cy = p[1], w = p[2], h = p[3];
        float hw = w * 0.5f, hh = h * 0.5f;
        float* o = out + ((size_t)img * MAX_DET + off) * 6;
        o[0] = cx - hw;
        o[1] = cy - hh;
        o[2] = cx + hw;
        o[3] = cy + hh;
        o[4] = __uint_as_float((uint32_t)(key >> 32));
        o[5] = (float)cc;
      }
      off++;
    }
  }
  uint32_t total = stot;
  if (total > MAX_DET) total = MAX_DET;
  for (int i = (int)total + tid; i < MAX_DET; i += 1024) {
    float* o = out + ((size_t)img * MAX_DET + i) * 6;
    o[0] = 0.f; o[1] = 0.f; o[2] = 0.f; o[3] = 0.f; o[4] = 0.f; o[5] = 0.f;
  }
}

extern "C" void kernel_launch(void* const* d_in, const int* in_sizes, int n_in,
                              void* d_out, int out_size, void* d_ws, size_t ws_size,
                              hipStream_t stream) {
  const float* pred = (const float*)d_in[0];
  float* out = (float*)d_out;
  char* ws = (char*)d_ws;

  u64*     crec   = (u64*)(ws + CREC_OFF);
  u64*     skey   = (u64*)(ws + SKEY_OFF);
  float4*  sobox  = (float4*)(ws + SOBOX_OFF);
  int*     hist   = (int*)(ws + HIST_OFF);
  int*     cnt    = (int*)(ws + CNT_OFF);
  uint8_t* salive = (uint8_t*)(ws + SALIVE_OFF);
  float*   thr    = (float*)(ws + THR_OFF);

  hipMemsetAsync(hist, 0, HIST_SZ + CNT_SZ, stream);
  hipMemsetAsync(salive, 0, SALIVE_SZ, stream);

  dim3 gbulk((N + 63) / 64, B);
  k_hist<<<gbulk, 256, 0, stream>>>(pred, hist);
  k_pivot<<<B, 256, 0, stream>>>(hist, thr);
  k_compact<<<gbulk, 256, 0, stream>>>(pred, thr, cnt, crec);
  k_sort<<<B, 1024, 0, stream>>>(cnt, crec, skey);
  dim3 gmat(16, B);
  k_mat<<<gmat, 256, 0, stream>>>(pred, skey, sobox);
  dim3 gnms(NC / 4, B);
  k_cnms<<<gnms, 256, 0, stream>>>(skey, sobox, salive);
  k_out<<<B, 1024, 0, stream>>>(pred, skey, salive, out);
}